// Round 1
// baseline (306.084 us; speedup 1.0000x reference)
//
#include <hip/hip_runtime.h>
#include <cstdint>
#include <cstddef>

#define B_    4
#define C_    64
#define N_    4096   // 64*64
#define DQ_   64
#define FPD_  128
#define SCALE_ 0.125f

typedef short bf16x8 __attribute__((ext_vector_type(8)));
typedef float f32x4  __attribute__((ext_vector_type(4)));

__device__ inline unsigned short f2bf(float f) {
    union { float f; unsigned int u; } v; v.f = f;
    unsigned int u = v.u;
    // round-to-nearest-even bf16 (inputs are finite, no NaN handling needed)
    return (unsigned short)((u + 0x7FFFu + ((u >> 16) & 1u)) >> 16);
}

// ---------------------------------------------------------------- kernel 0
__global__ __launch_bounds__(256) void fp_proj_kernel(
    const float* __restrict__ fp, const float* __restrict__ Wfp,
    const float* __restrict__ bfp, float* __restrict__ fp_proj)
{
    int tid = threadIdx.x;            // 256 = B*64
    int b = tid >> 6, d = tid & 63;
    float acc = bfp[d];
    for (int i = 0; i < FPD_; ++i)
        acc += fp[b * FPD_ + i] * Wfp[d * FPD_ + i];
    fp_proj[b * 64 + d] = acc;
}

// ---------------------------------------------------------------- helpers
__device__ inline void conv_tile(const float* Wl, const float* __restrict__ bias,
                                 const float* xs, int p, int dbase, float* acc)
{
    #pragma unroll
    for (int i = 0; i < 16; ++i) acc[i] = bias[dbase + i];
    for (int c = 0; c < 64; ++c) {
        float xv = xs[c * 64 + p];            // lane varies p -> 2-way bank (free)
        #pragma unroll
        for (int i = 0; i < 16; ++i)          // wave-uniform W read -> LDS broadcast
            acc[i] += Wl[(dbase + i) * 64 + c] * xv;
    }
}

// ---------------------------------------------------------------- kernel 1
// Per block: batch b, 64 spatial positions. Computes q,k,v (fp32), gate, and
// stores Q,K position-major bf16 [b][n][d], V channel-major bf16 [b][c][n].
__global__ __launch_bounds__(256) void qkv_kernel(
    const float* __restrict__ x,
    const float* __restrict__ Wq, const float* __restrict__ bq,
    const float* __restrict__ Wk, const float* __restrict__ bk,
    const float* __restrict__ Wv, const float* __restrict__ bv,
    const float* __restrict__ fp_proj, float* __restrict__ gate,
    unsigned short* __restrict__ Qb, unsigned short* __restrict__ Kb,
    unsigned short* __restrict__ Vb)
{
    __shared__ float xs[64 * 64];       // 16 KB: xs[c][p]
    __shared__ float Wl[3 * 4096];      // 48 KB: Wq,Wk,Wv (tail aliased as gpart)
    int tid = threadIdx.x;
    int blk = blockIdx.x;
    int b  = blk >> 6;
    int p0 = (blk & 63) << 6;
    const float* xb = x + (size_t)b * C_ * N_;

    for (int i = 0; i < 16; ++i) {
        int l = tid + i * 256;          // 0..4095
        int c = l >> 6, p = l & 63;
        xs[l] = xb[c * N_ + p0 + p];
    }
    for (int i = 0; i < 16; ++i) { int l = tid + i * 256; Wl[l]        = Wq[l]; }
    for (int i = 0; i < 16; ++i) { int l = tid + i * 256; Wl[4096 + l] = Wk[l]; }
    for (int i = 0; i < 16; ++i) { int l = tid + i * 256; Wl[8192 + l] = Wv[l]; }
    __syncthreads();

    int p  = tid & 63;
    int dg = tid >> 6;
    int dbase = __builtin_amdgcn_readfirstlane(dg << 4);   // wave-uniform -> s_loads

    float acc[16];
    // ---- Q ----
    conv_tile(Wl, bq, xs, p, dbase, acc);
    float gp = 0.f;
    #pragma unroll
    for (int i = 0; i < 16; ++i) gp += acc[i] * fp_proj[b * 64 + dbase + i];
    {
        unsigned short* dst = Qb + ((size_t)b * N_ + p0 + p) * 64 + dbase;
        #pragma unroll
        for (int i = 0; i < 16; i += 4) {
            ushort4 u4; u4.x = f2bf(acc[i]); u4.y = f2bf(acc[i+1]);
            u4.z = f2bf(acc[i+2]); u4.w = f2bf(acc[i+3]);
            *reinterpret_cast<ushort4*>(dst + i) = u4;
        }
    }
    // ---- K ----
    conv_tile(Wl + 4096, bk, xs, p, dbase, acc);
    {
        unsigned short* dst = Kb + ((size_t)b * N_ + p0 + p) * 64 + dbase;
        #pragma unroll
        for (int i = 0; i < 16; i += 4) {
            ushort4 u4; u4.x = f2bf(acc[i]); u4.y = f2bf(acc[i+1]);
            u4.z = f2bf(acc[i+2]); u4.w = f2bf(acc[i+3]);
            *reinterpret_cast<ushort4*>(dst + i) = u4;
        }
    }
    // ---- V (channel-major store) ----
    conv_tile(Wl + 8192, bv, xs, p, dbase, acc);
    #pragma unroll
    for (int i = 0; i < 16; ++i)
        Vb[((size_t)b * 64 + dbase + i) * N_ + p0 + p] = f2bf(acc[i]);

    // ---- gate reduce (alias Wl head after all reads done) ----
    __syncthreads();
    float* gpart = Wl;
    gpart[dg * 64 + p] = gp;
    __syncthreads();
    if (dg == 0) {
        float s = gpart[p] + gpart[64 + p] + gpart[128 + p] + gpart[192 + p];
        gate[b * N_ + p0 + p] = 1.f / (1.f + __expf(-s));
    }
}

// ---------------------------------------------------------------- kernel 2
// Flash attention, no-max softmax (scores bounded). 256 blocks = B x 64 qtiles,
// 4 waves x 16 q-rows. O = (sum_j e^s V) / (sum_j e^s), l via MFMA vs ones.
__global__ __launch_bounds__(256) void attn_kernel(
    const unsigned short* __restrict__ Qb, const unsigned short* __restrict__ Kb,
    const unsigned short* __restrict__ Vb, float* __restrict__ Oattn)
{
    __shared__ unsigned short Qs[64 * 72];   // [qi][d]  rows padded to 144 B
    __shared__ unsigned short Ks[64 * 72];   // [kj][d]
    __shared__ unsigned short Vs[64 * 72];   // [c][tj]
    __shared__ unsigned short Ps[64 * 72];   // [qi][tj] (per-wave 16-row strips)

    int tid = threadIdx.x;
    int bx  = blockIdx.x;
    // XCD swizzle: batch b pinned to XCD pair -> K/V (2MB) resident in 4MB L2
    int b  = (bx & 7) >> 1;
    int qt = ((bx >> 3) << 1) | (bx & 1);
    int q0 = qt << 6;

    int lane = tid & 63;
    int wv   = __builtin_amdgcn_readfirstlane(tid >> 6);
    int quad = lane >> 4, l16 = lane & 15;
    int qs0  = wv << 4;

    const unsigned short* Qg = Qb + ((size_t)b * N_ + q0) * 64;
    for (int i = 0; i < 4; ++i) {
        int u = tid + i * 256;                 // 1024 ushort4 units
        int qi = u >> 4, dc = (u & 15) << 2;
        *reinterpret_cast<ushort4*>(&Qs[qi * 72 + dc]) =
            *reinterpret_cast<const ushort4*>(&Qg[qi * 64 + dc]);
    }
    __syncthreads();

    // A-frags for Q (loop-invariant): A[m=l16][k=quad*8+j]
    bf16x8 aq0 = *reinterpret_cast<bf16x8*>(&Qs[(qs0 + l16) * 72 + quad * 8]);
    bf16x8 aq1 = *reinterpret_cast<bf16x8*>(&Qs[(qs0 + l16) * 72 + 32 + quad * 8]);

    f32x4 oacc[4]; f32x4 lacc;
    #pragma unroll
    for (int cs = 0; cs < 4; ++cs) oacc[cs] = (f32x4){0.f, 0.f, 0.f, 0.f};
    lacc = (f32x4){0.f, 0.f, 0.f, 0.f};
    bf16x8 ones;
    #pragma unroll
    for (int i = 0; i < 8; ++i) ones[i] = (short)0x3F80;   // bf16 1.0

    const unsigned short* Kg = Kb + (size_t)b * N_ * 64;
    const unsigned short* Vg = Vb + (size_t)b * 64 * N_;

    for (int kt = 0; kt < 64; ++kt) {
        int k0 = kt << 6;
        __syncthreads();                       // prior-iter frag reads done
        for (int i = 0; i < 4; ++i) {
            int u = tid + i * 256;
            int r = u >> 4, cc = (u & 15) << 2;
            *reinterpret_cast<ushort4*>(&Ks[r * 72 + cc]) =
                *reinterpret_cast<const ushort4*>(&Kg[(k0 + r) * 64 + cc]);
            *reinterpret_cast<ushort4*>(&Vs[r * 72 + cc]) =
                *reinterpret_cast<const ushort4*>(&Vg[r * N_ + k0 + cc]);
        }
        __syncthreads();

        // S = Q K^T, P = exp(S/8) -> LDS (layout transform C/D -> A)
        #pragma unroll
        for (int kj = 0; kj < 4; ++kj) {
            bf16x8 bk0 = *reinterpret_cast<bf16x8*>(&Ks[(kj * 16 + l16) * 72 + quad * 8]);
            bf16x8 bk1 = *reinterpret_cast<bf16x8*>(&Ks[(kj * 16 + l16) * 72 + 32 + quad * 8]);
            f32x4 s = (f32x4){0.f, 0.f, 0.f, 0.f};
            s = __builtin_amdgcn_mfma_f32_16x16x32_bf16(aq0, bk0, s, 0, 0, 0);
            s = __builtin_amdgcn_mfma_f32_16x16x32_bf16(aq1, bk1, s, 0, 0, 0);
            #pragma unroll
            for (int j = 0; j < 4; ++j) {
                float pv = __expf(s[j] * SCALE_);
                Ps[(qs0 + quad * 4 + j) * 72 + kj * 16 + l16] = f2bf(pv);
            }
        }
        __asm__ volatile("s_waitcnt lgkmcnt(0)" ::: "memory");  // wave-local P strip

        bf16x8 ap0 = *reinterpret_cast<bf16x8*>(&Ps[(qs0 + l16) * 72 + quad * 8]);
        bf16x8 ap1 = *reinterpret_cast<bf16x8*>(&Ps[(qs0 + l16) * 72 + 32 + quad * 8]);
        // row-sums l += P @ ones   (same C/D row layout as oacc)
        lacc = __builtin_amdgcn_mfma_f32_16x16x32_bf16(ap0, ones, lacc, 0, 0, 0);
        lacc = __builtin_amdgcn_mfma_f32_16x16x32_bf16(ap1, ones, lacc, 0, 0, 0);
        #pragma unroll
        for (int cs = 0; cs < 4; ++cs) {
            bf16x8 bv0 = *reinterpret_cast<bf16x8*>(&Vs[(cs * 16 + l16) * 72 + quad * 8]);
            bf16x8 bv1 = *reinterpret_cast<bf16x8*>(&Vs[(cs * 16 + l16) * 72 + 32 + quad * 8]);
            oacc[cs] = __builtin_amdgcn_mfma_f32_16x16x32_bf16(ap0, bv0, oacc[cs], 0, 0, 0);
            oacc[cs] = __builtin_amdgcn_mfma_f32_16x16x32_bf16(ap1, bv1, oacc[cs], 0, 0, 0);
        }
    }

    // normalize + store position-major [b][n][c] fp32
    float* Og = Oattn + ((size_t)b * N_ + q0) * 64;
    #pragma unroll
    for (int j = 0; j < 4; ++j) {
        float inv = 1.f / lacc[j];
        int row = qs0 + quad * 4 + j;
        #pragma unroll
        for (int cs = 0; cs < 4; ++cs)
            Og[row * 64 + cs * 16 + l16] = oacc[cs][j] * inv;
    }
}

// ---------------------------------------------------------------- kernel 3
// out = Wo @ (Oattn*gate + x) + bo
__global__ __launch_bounds__(256) void epi_kernel(
    const float* __restrict__ Oattn, const float* __restrict__ x,
    const float* __restrict__ gate, const float* __restrict__ Wo,
    const float* __restrict__ bo, float* __restrict__ out)
{
    __shared__ float os[64 * 65];   // [p][c] padded (p varies across lanes)
    __shared__ float xs[64 * 64];   // [c][p]
    __shared__ float Wl[64 * 64];
    int tid = threadIdx.x;
    int blk = blockIdx.x;
    int b  = blk >> 6;
    int p0 = (blk & 63) << 6;
    const float* xb = x + (size_t)b * C_ * N_;
    const float* Ob = Oattn + ((size_t)b * N_ + p0) * 64;

    for (int i = 0; i < 16; ++i) {
        int l = tid + i * 256;
        int p = l >> 6, c = l & 63;
        os[p * 65 + c] = Ob[p * 64 + c];
    }
    for (int i = 0; i < 16; ++i) {
        int l = tid + i * 256;
        int c = l >> 6, p = l & 63;
        xs[l] = xb[c * N_ + p0 + p];
    }
    for (int i = 0; i < 16; ++i) { int l = tid + i * 256; Wl[l] = Wo[l]; }
    __syncthreads();

    int p  = tid & 63;
    int dg = tid >> 6;
    int dbase = __builtin_amdgcn_readfirstlane(dg << 4);
    float g = gate[b * N_ + p0 + p];

    float acc[16];
    #pragma unroll
    for (int i = 0; i < 16; ++i) acc[i] = bo[dbase + i];
    for (int c = 0; c < 64; ++c) {
        float t = os[p * 65 + c] * g + xs[c * 64 + p];
        #pragma unroll
        for (int i = 0; i < 16; ++i)
            acc[i] += Wl[(dbase + i) * 64 + c] * t;
    }
    float* ob = out + (size_t)b * C_ * N_;
    #pragma unroll
    for (int i = 0; i < 16; ++i)
        ob[(dbase + i) * N_ + p0 + p] = acc[i];
}

// ---------------------------------------------------------------- launch
extern "C" void kernel_launch(void* const* d_in, const int* in_sizes, int n_in,
                              void* d_out, int out_size, void* d_ws, size_t ws_size,
                              hipStream_t stream)
{
    const float* x   = (const float*)d_in[0];
    const float* fp  = (const float*)d_in[1];
    const float* Wq  = (const float*)d_in[2];
    const float* bq  = (const float*)d_in[3];
    const float* Wk  = (const float*)d_in[4];
    const float* bk  = (const float*)d_in[5];
    const float* Wv  = (const float*)d_in[6];
    const float* bv  = (const float*)d_in[7];
    const float* Wo  = (const float*)d_in[8];
    const float* bo  = (const float*)d_in[9];
    const float* Wfp = (const float*)d_in[10];
    const float* bfp = (const float*)d_in[11];
    float* out = (float*)d_out;

    char* ws = (char*)d_ws;
    float* fp_proj = (float*)(ws);                               // 1 KB
    float* gate    = (float*)(ws + 1024);                        // 64 KB
    unsigned short* Qb = (unsigned short*)(ws + 66560);          // 2 MB
    unsigned short* Kb = (unsigned short*)(ws + 66560 + 2097152);
    unsigned short* Vb = (unsigned short*)(ws + 66560 + 2 * 2097152);
    float* Oattn = (float*)(ws + 66560 + 3 * 2097152);           // 4 MB

    hipLaunchKernelGGL(fp_proj_kernel, dim3(1), dim3(256), 0, stream,
                       fp, Wfp, bfp, fp_proj);
    hipLaunchKernelGGL(qkv_kernel, dim3(256), dim3(256), 0, stream,
                       x, Wq, bq, Wk, bk, Wv, bv, fp_proj, gate, Qb, Kb, Vb);
    hipLaunchKernelGGL(attn_kernel, dim3(256), dim3(256), 0, stream,
                       Qb, Kb, Vb, Oattn);
    hipLaunchKernelGGL(epi_kernel, dim3(256), dim3(256), 0, stream,
                       Oattn, x, gate, Wo, bo, out);
}

// Round 2
// 199.817 us; speedup vs baseline: 1.5318x; 1.5318x over previous
//
#include <hip/hip_runtime.h>
#include <cstdint>
#include <cstddef>

#define B_    4
#define C_    64
#define N_    4096   // 64*64
#define FPD_  128
// fold (1/sqrt(64)) * log2(e) into stored Q so attn does pv = exp2(s)
#define QSCALE_ (0.125f * 1.4426950408889634f)

typedef short bf16x8 __attribute__((ext_vector_type(8)));
typedef float f32x4  __attribute__((ext_vector_type(4)));

__device__ inline unsigned short f2bf(float f) {
    union { float f; unsigned int u; } v; v.f = f;
    unsigned int u = v.u;
    return (unsigned short)((u + 0x7FFFu + ((u >> 16) & 1u)) >> 16);  // RNE
}

// ---------------------------------------------------------------- kernel 0
__global__ __launch_bounds__(256) void fp_proj_kernel(
    const float* __restrict__ fp, const float* __restrict__ Wfp,
    const float* __restrict__ bfp, float* __restrict__ fp_proj)
{
    int tid = threadIdx.x;            // 256 = B*64
    int b = tid >> 6, d = tid & 63;
    float acc = bfp[d];
    for (int i = 0; i < FPD_; ++i)
        acc = fmaf(fp[b * FPD_ + i], Wfp[d * FPD_ + i], acc);
    fp_proj[b * 64 + d] = acc;
}

// ---------------------------------------------------------------- kernel 1
// x column in VGPRs; W at wave-uniform addresses from global (-> s_load,
// scalar pipe); all three convs accumulated in one pass over c.
__global__ __launch_bounds__(256) void qkv_kernel(
    const float* __restrict__ x,
    const float* __restrict__ Wq, const float* __restrict__ bq,
    const float* __restrict__ Wk, const float* __restrict__ bk,
    const float* __restrict__ Wv, const float* __restrict__ bv,
    const float* __restrict__ fp_proj, float* __restrict__ gate,
    unsigned short* __restrict__ Qb, unsigned short* __restrict__ Kb,
    unsigned short* __restrict__ Vb)
{
    __shared__ float gred[256];
    int tid = threadIdx.x;
    int b  = blockIdx.x >> 6;
    int p0 = (blockIdx.x & 63) << 6;
    int p  = tid & 63;
    int wid = tid >> 6;
    int dbase = __builtin_amdgcn_readfirstlane(wid << 4);
    int q = p0 + p;
    const float* xp = x + (size_t)b * (C_ * N_) + q;

    float accq[16], acck[16], accv[16];
    #pragma unroll
    for (int i = 0; i < 16; ++i) {
        accq[i] = bq[dbase + i];
        acck[i] = bk[dbase + i];
        accv[i] = bv[dbase + i];
    }

    for (int cc = 0; cc < 4; ++cc) {
        float xc[16];
        #pragma unroll
        for (int j = 0; j < 16; ++j) xc[j] = xp[(size_t)(cc * 16 + j) * N_];
        #pragma unroll
        for (int j = 0; j < 16; ++j) {
            int c = cc * 16 + j;               // wave-uniform index into W
            float v = xc[j];
            #pragma unroll
            for (int i = 0; i < 16; ++i) {
                accq[i] = fmaf(Wq[(dbase + i) * 64 + c], v, accq[i]);
                acck[i] = fmaf(Wk[(dbase + i) * 64 + c], v, acck[i]);
                accv[i] = fmaf(Wv[(dbase + i) * 64 + c], v, accv[i]);
            }
        }
    }

    // gate partial: <q_unscaled, fp_proj> over this wave's 16 channels
    float gp = 0.f;
    #pragma unroll
    for (int i = 0; i < 16; ++i)
        gp = fmaf(accq[i], fp_proj[b * 64 + dbase + i], gp);
    gred[tid] = gp;
    __syncthreads();
    if (wid == 0) {
        float s = gred[p] + gred[64 + p] + gred[128 + p] + gred[192 + p];
        gate[b * N_ + q] = 1.f / (1.f + __expf(-s));
    }

    // stores: Q (pre-scaled), K position-major bf16; V channel-major bf16
    unsigned short* qd = Qb + ((size_t)b * N_ + q) * 64 + dbase;
    unsigned short* kd = Kb + ((size_t)b * N_ + q) * 64 + dbase;
    #pragma unroll
    for (int i = 0; i < 16; i += 4) {
        ushort4 uq, uk;
        uq.x = f2bf(accq[i+0] * QSCALE_); uq.y = f2bf(accq[i+1] * QSCALE_);
        uq.z = f2bf(accq[i+2] * QSCALE_); uq.w = f2bf(accq[i+3] * QSCALE_);
        uk.x = f2bf(acck[i+0]); uk.y = f2bf(acck[i+1]);
        uk.z = f2bf(acck[i+2]); uk.w = f2bf(acck[i+3]);
        *reinterpret_cast<ushort4*>(qd + i) = uq;
        *reinterpret_cast<ushort4*>(kd + i) = uk;
    }
    #pragma unroll
    for (int i = 0; i < 16; ++i)
        Vb[((size_t)b * 64 + dbase + i) * N_ + q] = f2bf(accv[i]);
}

// ---------------------------------------------------------------- kernel 2
// Flash attention, no-max softmax, K-SPLIT x4 (additive: no online max).
// Grid 1024 = B x 64 qtiles x 4 ksplits -> 4 blocks/CU. Partial O and l
// accumulated into fp32 via atomics (zeroed by hipMemsetAsync).
__global__ __launch_bounds__(256, 4) void attn_kernel(
    const unsigned short* __restrict__ Qb, const unsigned short* __restrict__ Kb,
    const unsigned short* __restrict__ Vb, float* __restrict__ Oattn,
    float* __restrict__ lsum)
{
    __shared__ unsigned short Ks[64 * 72];   // [kj][d]  rows padded to 144 B
    __shared__ unsigned short Vs[64 * 72];   // [c][tj]
    __shared__ unsigned short Ps[64 * 72];   // [qi][tj] per-wave strips

    int tid = threadIdx.x;
    int bx  = blockIdx.x;          // 1024
    int qt  = bx >> 4;             // 0..63
    int grp = bx & 15;             // (b, ks); bx&7 round-robins XCDs
    int b   = grp >> 2;
    int ks  = grp & 3;
    int q0  = qt << 6;
    int kbase = ks << 10;          // 1024-column K window

    int lane = tid & 63;
    int wv   = __builtin_amdgcn_readfirstlane(tid >> 6);
    int quad = lane >> 4, l16 = lane & 15;
    int qs0  = wv << 4;

    // Q A-frags straight from global (16B aligned): A[m=l16][k=quad*8+j]
    const unsigned short* Qg = Qb + ((size_t)b * N_ + q0) * 64;
    bf16x8 aq0 = *reinterpret_cast<const bf16x8*>(&Qg[(qs0 + l16) * 64 + quad * 8]);
    bf16x8 aq1 = *reinterpret_cast<const bf16x8*>(&Qg[(qs0 + l16) * 64 + 32 + quad * 8]);

    const unsigned short* Kg = Kb + ((size_t)b * N_ + kbase) * 64;
    const unsigned short* Vg = Vb + (size_t)b * 64 * N_ + kbase;

    int r0 = tid >> 4;             // staging row 0..15 (+16*i)
    int cc = (tid & 15) << 2;      // staging col (ushort4 units)

    ushort4 kr[4], vr[4];
    #pragma unroll
    for (int i = 0; i < 4; ++i) {
        int r = r0 + 16 * i;
        kr[i] = *reinterpret_cast<const ushort4*>(&Kg[(size_t)r * 64 + cc]);
        vr[i] = *reinterpret_cast<const ushort4*>(&Vg[(size_t)r * N_ + cc]);
    }

    f32x4 oacc[4]; f32x4 lacc = (f32x4){0.f, 0.f, 0.f, 0.f};
    #pragma unroll
    for (int cs = 0; cs < 4; ++cs) oacc[cs] = (f32x4){0.f, 0.f, 0.f, 0.f};
    bf16x8 ones;
    #pragma unroll
    for (int i = 0; i < 8; ++i) ones[i] = (short)0x3F80;   // bf16 1.0

    for (int kt = 0; kt < 16; ++kt) {
        __syncthreads();                     // prev-iter frag reads done
        #pragma unroll
        for (int i = 0; i < 4; ++i) {
            int r = r0 + 16 * i;
            *reinterpret_cast<ushort4*>(&Ks[r * 72 + cc]) = kr[i];
            *reinterpret_cast<ushort4*>(&Vs[r * 72 + cc]) = vr[i];
        }
        __syncthreads();
        if (kt < 15) {                       // prefetch next tile (overlaps compute)
            int kk = (kt + 1) << 6;
            #pragma unroll
            for (int i = 0; i < 4; ++i) {
                int r = r0 + 16 * i;
                kr[i] = *reinterpret_cast<const ushort4*>(&Kg[(size_t)(kk + r) * 64 + cc]);
                vr[i] = *reinterpret_cast<const ushort4*>(&Vg[(size_t)r * N_ + kk + cc]);
            }
        }

        // S = Q K^T (scale pre-folded), P = exp2(S) -> LDS (C/D -> A transform)
        #pragma unroll
        for (int kj = 0; kj < 4; ++kj) {
            bf16x8 bk0 = *reinterpret_cast<bf16x8*>(&Ks[(kj * 16 + l16) * 72 + quad * 8]);
            bf16x8 bk1 = *reinterpret_cast<bf16x8*>(&Ks[(kj * 16 + l16) * 72 + 32 + quad * 8]);
            f32x4 s = (f32x4){0.f, 0.f, 0.f, 0.f};
            s = __builtin_amdgcn_mfma_f32_16x16x32_bf16(aq0, bk0, s, 0, 0, 0);
            s = __builtin_amdgcn_mfma_f32_16x16x32_bf16(aq1, bk1, s, 0, 0, 0);
            #pragma unroll
            for (int j = 0; j < 4; ++j) {
                float pv = exp2f(s[j]);      // v_exp_f32
                Ps[(qs0 + quad * 4 + j) * 72 + kj * 16 + l16] = f2bf(pv);
            }
        }
        __asm__ volatile("s_waitcnt lgkmcnt(0)" ::: "memory");  // wave-local strip

        bf16x8 ap0 = *reinterpret_cast<bf16x8*>(&Ps[(qs0 + l16) * 72 + quad * 8]);
        bf16x8 ap1 = *reinterpret_cast<bf16x8*>(&Ps[(qs0 + l16) * 72 + 32 + quad * 8]);
        lacc = __builtin_amdgcn_mfma_f32_16x16x32_bf16(ap0, ones, lacc, 0, 0, 0);
        lacc = __builtin_amdgcn_mfma_f32_16x16x32_bf16(ap1, ones, lacc, 0, 0, 0);
        #pragma unroll
        for (int cs = 0; cs < 4; ++cs) {
            bf16x8 bv0 = *reinterpret_cast<bf16x8*>(&Vs[(cs * 16 + l16) * 72 + quad * 8]);
            bf16x8 bv1 = *reinterpret_cast<bf16x8*>(&Vs[(cs * 16 + l16) * 72 + 32 + quad * 8]);
            oacc[cs] = __builtin_amdgcn_mfma_f32_16x16x32_bf16(ap0, bv0, oacc[cs], 0, 0, 0);
            oacc[cs] = __builtin_amdgcn_mfma_f32_16x16x32_bf16(ap1, bv1, oacc[cs], 0, 0, 0);
        }
    }

    // accumulate partials (4 adds per address across ksplits)
    float* Og = Oattn + ((size_t)b * N_ + q0) * 64;
    #pragma unroll
    for (int j = 0; j < 4; ++j) {
        int row = qs0 + quad * 4 + j;
        #pragma unroll
        for (int cs = 0; cs < 4; ++cs)
            unsafeAtomicAdd(&Og[row * 64 + cs * 16 + l16], oacc[cs][j]);
    }
    if (l16 == 0) {
        #pragma unroll
        for (int j = 0; j < 4; ++j)
            unsafeAtomicAdd(&lsum[b * N_ + q0 + qs0 + quad * 4 + j], lacc[j]);
    }
}

// ---------------------------------------------------------------- kernel 3
// out = Wo @ (Oattn/l * gate + x) + bo ; t[] in VGPRs, Wo via scalar loads
__global__ __launch_bounds__(256) void epi_kernel(
    const float* __restrict__ Oattn, const float* __restrict__ lsum,
    const float* __restrict__ x, const float* __restrict__ gate,
    const float* __restrict__ Wo, const float* __restrict__ bo,
    float* __restrict__ out)
{
    int tid = threadIdx.x;
    int b  = blockIdx.x >> 6;
    int p0 = (blockIdx.x & 63) << 6;
    int p  = tid & 63;
    int dbase = __builtin_amdgcn_readfirstlane((tid >> 6) << 4);
    int q = p0 + p;

    float gi = gate[b * N_ + q] / lsum[b * N_ + q];
    const float* Op = Oattn + ((size_t)b * N_ + q) * 64;
    const float* xp = x + (size_t)b * (C_ * N_) + q;

    float t[64];
    #pragma unroll
    for (int c4 = 0; c4 < 16; ++c4) {
        float4 o4 = reinterpret_cast<const float4*>(Op)[c4];
        t[4 * c4 + 0] = fmaf(o4.x, gi, xp[(size_t)(4 * c4 + 0) * N_]);
        t[4 * c4 + 1] = fmaf(o4.y, gi, xp[(size_t)(4 * c4 + 1) * N_]);
        t[4 * c4 + 2] = fmaf(o4.z, gi, xp[(size_t)(4 * c4 + 2) * N_]);
        t[4 * c4 + 3] = fmaf(o4.w, gi, xp[(size_t)(4 * c4 + 3) * N_]);
    }

    float acc[16];
    #pragma unroll
    for (int i = 0; i < 16; ++i) acc[i] = bo[dbase + i];
    #pragma unroll
    for (int c = 0; c < 64; ++c) {
        float tc = t[c];
        #pragma unroll
        for (int i = 0; i < 16; ++i)
            acc[i] = fmaf(Wo[(dbase + i) * 64 + c], tc, acc[i]);
    }
    float* ob = out + (size_t)b * (C_ * N_) + q;
    #pragma unroll
    for (int i = 0; i < 16; ++i)
        ob[(size_t)(dbase + i) * N_] = acc[i];
}

// ---------------------------------------------------------------- launch
extern "C" void kernel_launch(void* const* d_in, const int* in_sizes, int n_in,
                              void* d_out, int out_size, void* d_ws, size_t ws_size,
                              hipStream_t stream)
{
    const float* x   = (const float*)d_in[0];
    const float* fp  = (const float*)d_in[1];
    const float* Wq  = (const float*)d_in[2];
    const float* bq  = (const float*)d_in[3];
    const float* Wk  = (const float*)d_in[4];
    const float* bk  = (const float*)d_in[5];
    const float* Wv  = (const float*)d_in[6];
    const float* bv  = (const float*)d_in[7];
    const float* Wo  = (const float*)d_in[8];
    const float* bo  = (const float*)d_in[9];
    const float* Wfp = (const float*)d_in[10];
    const float* bfp = (const float*)d_in[11];
    float* out = (float*)d_out;

    char* ws = (char*)d_ws;
    float* fp_proj = (float*)(ws);                                   // 1 KB
    float* gate    = (float*)(ws + 1024);                            // 64 KB
    unsigned short* Qb = (unsigned short*)(ws + 66560);              // 2 MB
    unsigned short* Kb = (unsigned short*)(ws + 66560 + 2097152);    // 2 MB
    unsigned short* Vb = (unsigned short*)(ws + 66560 + 2 * 2097152);// 2 MB
    float* Oattn = (float*)(ws + 66560 + 3 * 2097152);               // 4 MB
    float* lsum  = (float*)(ws + 66560 + 3 * 2097152 + 4194304);     // 64 KB

    hipMemsetAsync(Oattn, 0, 4194304 + 65536, stream);   // O + l accumulators

    hipLaunchKernelGGL(fp_proj_kernel, dim3(1), dim3(256), 0, stream,
                       fp, Wfp, bfp, fp_proj);
    hipLaunchKernelGGL(qkv_kernel, dim3(256), dim3(256), 0, stream,
                       x, Wq, bq, Wk, bk, Wv, bv, fp_proj, gate, Qb, Kb, Vb);
    hipLaunchKernelGGL(attn_kernel, dim3(1024), dim3(256), 0, stream,
                       Qb, Kb, Vb, Oattn, lsum);
    hipLaunchKernelGGL(epi_kernel, dim3(256), dim3(256), 0, stream,
                       Oattn, lsum, x, gate, Wo, bo, out);
}

// Round 3
// 145.875 us; speedup vs baseline: 2.0983x; 1.3698x over previous
//
#include <hip/hip_runtime.h>
#include <cstdint>
#include <cstddef>

#define B_    4
#define C_    64
#define N_    4096   // 64*64
#define FPD_  128
// fold (1/sqrt(64)) * log2(e) into stored Q so attn does pv = exp2(s)
#define QSCALE_ (0.125f * 1.4426950408889634f)

typedef short bf16x8 __attribute__((ext_vector_type(8)));
typedef float f32x4  __attribute__((ext_vector_type(4)));

__device__ inline unsigned short f2bf(float f) {
    union { float f; unsigned int u; } v; v.f = f;
    unsigned int u = v.u;
    return (unsigned short)((u + 0x7FFFu + ((u >> 16) & 1u)) >> 16);  // RNE
}

// ---------------------------------------------------------------- kernel 0
// Block 0: fp_proj gemm + scaled biases. Blocks 1..64: W -> bf16 conversion.
// Wb layout: rows 0-63 = Wq*QSCALE, 64-127 = Wk, 128-191 = Wv, 192-255 = Wo.
__global__ __launch_bounds__(256) void prep_kernel(
    const float* __restrict__ fp, const float* __restrict__ Wfp,
    const float* __restrict__ bfp,
    const float* __restrict__ Wq, const float* __restrict__ bq,
    const float* __restrict__ Wk, const float* __restrict__ bk,
    const float* __restrict__ Wv, const float* __restrict__ bv,
    const float* __restrict__ Wo,
    float* __restrict__ fp_proj, unsigned short* __restrict__ Wb,
    float* __restrict__ bs)
{
    int tid = threadIdx.x;
    if (blockIdx.x == 0) {
        int b = tid >> 6, d = tid & 63;
        float acc = bfp[d];
        for (int i = 0; i < FPD_; ++i)
            acc = fmaf(fp[b * FPD_ + i], Wfp[d * FPD_ + i], acc);
        fp_proj[b * 64 + d] = acc;
        if (tid < 64) {
            bs[tid]       = bq[tid] * QSCALE_;
            bs[64 + tid]  = bk[tid];
            bs[128 + tid] = bv[tid];
        }
    } else {
        int g = (blockIdx.x - 1) * 256 + tid;   // 0..16383
        int which = g >> 12, l = g & 4095;
        float v;
        if (which == 0)      v = Wq[l] * QSCALE_;
        else if (which == 1) v = Wk[l];
        else if (which == 2) v = Wv[l];
        else                 v = Wo[l];
        Wb[g] = f2bf(v);
    }
}

// ---------------------------------------------------------------- kernel 1
// MFMA QKV: out[192,p] = Wb[192,64] @ xT[64,p] per 64-position tile.
// B-frags from LDS xT (bf16), A-frags coalesced from global Wb (L2-hot).
// Q/K repacked via LDS -> coalesced position-major stores; V -> channel-major.
__global__ __launch_bounds__(256) void qkv_kernel(
    const float* __restrict__ x, const unsigned short* __restrict__ Wb,
    const float* __restrict__ bs, const float* __restrict__ fp_proj,
    float* __restrict__ gate,
    unsigned short* __restrict__ Qb, unsigned short* __restrict__ Kb,
    unsigned short* __restrict__ Vb)
{
    __shared__ unsigned short xT[64 * 72];   // [p][c] bf16, stride 72
    __shared__ unsigned short rp[64 * 72];   // repack buffer

    int tid = threadIdx.x;
    int b  = blockIdx.x >> 6;
    int p0 = (blockIdx.x & 63) << 6;
    const float* xb = x + (size_t)b * (C_ * N_) + p0;

    // stage x tile transposed to [p][c] bf16
    for (int i = 0; i < 16; ++i) {
        int l = tid + i * 256;          // 0..4095
        int c = l >> 6, p = l & 63;
        xT[p * 72 + c] = f2bf(xb[(size_t)c * N_ + p]);
    }
    __syncthreads();

    int lane = tid & 63;
    int wv   = __builtin_amdgcn_readfirstlane(tid >> 6);   // p-tile
    int quad = lane >> 4, l16 = lane & 15;
    int prow = wv * 16 + l16;

    // loop-invariant B-frags (x) for this wave's 16 positions
    bf16x8 bx0 = *reinterpret_cast<bf16x8*>(&xT[prow * 72 + quad * 8]);
    bf16x8 bx1 = *reinterpret_cast<bf16x8*>(&xT[prow * 72 + 32 + quad * 8]);

    float gp = 0.f;

    for (int pass = 0; pass < 3; ++pass) {      // Q, K, V
        #pragma unroll
        for (int t4 = 0; t4 < 4; ++t4) {
            int ot = pass * 4 + t4;             // o-tile 0..11
            const unsigned short* Wg = Wb + ot * 1024;
            bf16x8 a0 = *reinterpret_cast<const bf16x8*>(&Wg[l16 * 64 + quad * 8]);
            bf16x8 a1 = *reinterpret_cast<const bf16x8*>(&Wg[l16 * 64 + 32 + quad * 8]);
            f32x4 c4 = (f32x4){0.f, 0.f, 0.f, 0.f};
            c4 = __builtin_amdgcn_mfma_f32_16x16x32_bf16(a0, bx0, c4, 0, 0, 0);
            c4 = __builtin_amdgcn_mfma_f32_16x16x32_bf16(a1, bx1, c4, 0, 0, 0);
            float4 bias = *reinterpret_cast<const float4*>(&bs[ot * 16 + quad * 4]);
            c4[0] += bias.x; c4[1] += bias.y; c4[2] += bias.z; c4[3] += bias.w;
            if (pass == 0) {                    // gate: scaled q . fp_proj
                float4 fpp = *reinterpret_cast<const float4*>(
                                 &fp_proj[b * 64 + t4 * 16 + quad * 4]);
                gp = fmaf(c4[0], fpp.x, gp); gp = fmaf(c4[1], fpp.y, gp);
                gp = fmaf(c4[2], fpp.z, gp); gp = fmaf(c4[3], fpp.w, gp);
            }
            if (pass < 2) {
                // rp[p][d]: row = position, col = d (within this conv)
                int dd = t4 * 16 + quad * 4;
                ushort2 u01, u23;
                u01.x = f2bf(c4[0]); u01.y = f2bf(c4[1]);
                u23.x = f2bf(c4[2]); u23.y = f2bf(c4[3]);
                *reinterpret_cast<ushort2*>(&rp[prow * 72 + dd])     = u01;
                *reinterpret_cast<ushort2*>(&rp[prow * 72 + dd + 2]) = u23;
            } else {
                // rp[c][p]: row = v-channel, col = position
                #pragma unroll
                for (int j = 0; j < 4; ++j)
                    rp[(t4 * 16 + quad * 4 + j) * 72 + prow] = f2bf(c4[j]);
            }
        }
        if (pass == 0) {                        // gate reduce across quads
            gp += __shfl_xor(gp, 16);
            gp += __shfl_xor(gp, 32);
            if (l16 == 0 && quad == 0) { /* noop: keep lanes 0-15 path below */ }
            if (lane < 16) {
                int pos = p0 + wv * 16 + lane;
                float s = gp * (1.0f / QSCALE_);
                gate[b * N_ + pos] = 1.f / (1.f + __expf(-s));
            }
        }
        __syncthreads();                        // rp filled
        // coalesced store from rp
        int row = tid >> 2;
        int cb  = (tid & 3) << 4;
        ushort4 u[4];
        #pragma unroll
        for (int k = 0; k < 4; ++k)
            u[k] = *reinterpret_cast<ushort4*>(&rp[row * 72 + cb + k * 4]);
        if (pass == 0) {
            unsigned short* dst = Qb + ((size_t)b * N_ + p0 + row) * 64 + cb;
            #pragma unroll
            for (int k = 0; k < 4; ++k)
                *reinterpret_cast<ushort4*>(dst + k * 4) = u[k];
        } else if (pass == 1) {
            unsigned short* dst = Kb + ((size_t)b * N_ + p0 + row) * 64 + cb;
            #pragma unroll
            for (int k = 0; k < 4; ++k)
                *reinterpret_cast<ushort4*>(dst + k * 4) = u[k];
        } else {
            unsigned short* dst = Vb + ((size_t)b * 64 + row) * N_ + p0 + cb;
            #pragma unroll
            for (int k = 0; k < 4; ++k)
                *reinterpret_cast<ushort4*>(dst + k * 4) = u[k];
        }
        __syncthreads();                        // rp free for next pass
    }
}

// ---------------------------------------------------------------- kernel 2
// Flash attention, no-max softmax, K-SPLIT x4 (additive). Unchanged.
__global__ __launch_bounds__(256, 4) void attn_kernel(
    const unsigned short* __restrict__ Qb, const unsigned short* __restrict__ Kb,
    const unsigned short* __restrict__ Vb, float* __restrict__ Oattn,
    float* __restrict__ lsum)
{
    __shared__ unsigned short Ks[64 * 72];
    __shared__ unsigned short Vs[64 * 72];
    __shared__ unsigned short Ps[64 * 72];

    int tid = threadIdx.x;
    int bx  = blockIdx.x;          // 1024
    int qt  = bx >> 4;
    int grp = bx & 15;
    int b   = grp >> 2;
    int ks  = grp & 3;
    int q0  = qt << 6;
    int kbase = ks << 10;

    int lane = tid & 63;
    int wv   = __builtin_amdgcn_readfirstlane(tid >> 6);
    int quad = lane >> 4, l16 = lane & 15;
    int qs0  = wv << 4;

    const unsigned short* Qg = Qb + ((size_t)b * N_ + q0) * 64;
    bf16x8 aq0 = *reinterpret_cast<const bf16x8*>(&Qg[(qs0 + l16) * 64 + quad * 8]);
    bf16x8 aq1 = *reinterpret_cast<const bf16x8*>(&Qg[(qs0 + l16) * 64 + 32 + quad * 8]);

    const unsigned short* Kg = Kb + ((size_t)b * N_ + kbase) * 64;
    const unsigned short* Vg = Vb + (size_t)b * 64 * N_ + kbase;

    int r0 = tid >> 4;
    int cc = (tid & 15) << 2;

    ushort4 kr[4], vr[4];
    #pragma unroll
    for (int i = 0; i < 4; ++i) {
        int r = r0 + 16 * i;
        kr[i] = *reinterpret_cast<const ushort4*>(&Kg[(size_t)r * 64 + cc]);
        vr[i] = *reinterpret_cast<const ushort4*>(&Vg[(size_t)r * N_ + cc]);
    }

    f32x4 oacc[4]; f32x4 lacc = (f32x4){0.f, 0.f, 0.f, 0.f};
    #pragma unroll
    for (int cs = 0; cs < 4; ++cs) oacc[cs] = (f32x4){0.f, 0.f, 0.f, 0.f};
    bf16x8 ones;
    #pragma unroll
    for (int i = 0; i < 8; ++i) ones[i] = (short)0x3F80;

    for (int kt = 0; kt < 16; ++kt) {
        __syncthreads();
        #pragma unroll
        for (int i = 0; i < 4; ++i) {
            int r = r0 + 16 * i;
            *reinterpret_cast<ushort4*>(&Ks[r * 72 + cc]) = kr[i];
            *reinterpret_cast<ushort4*>(&Vs[r * 72 + cc]) = vr[i];
        }
        __syncthreads();
        if (kt < 15) {
            int kk = (kt + 1) << 6;
            #pragma unroll
            for (int i = 0; i < 4; ++i) {
                int r = r0 + 16 * i;
                kr[i] = *reinterpret_cast<const ushort4*>(&Kg[(size_t)(kk + r) * 64 + cc]);
                vr[i] = *reinterpret_cast<const ushort4*>(&Vg[(size_t)r * N_ + kk + cc]);
            }
        }

        #pragma unroll
        for (int kj = 0; kj < 4; ++kj) {
            bf16x8 bk0 = *reinterpret_cast<bf16x8*>(&Ks[(kj * 16 + l16) * 72 + quad * 8]);
            bf16x8 bk1 = *reinterpret_cast<bf16x8*>(&Ks[(kj * 16 + l16) * 72 + 32 + quad * 8]);
            f32x4 s = (f32x4){0.f, 0.f, 0.f, 0.f};
            s = __builtin_amdgcn_mfma_f32_16x16x32_bf16(aq0, bk0, s, 0, 0, 0);
            s = __builtin_amdgcn_mfma_f32_16x16x32_bf16(aq1, bk1, s, 0, 0, 0);
            #pragma unroll
            for (int j = 0; j < 4; ++j) {
                float pv = exp2f(s[j]);
                Ps[(qs0 + quad * 4 + j) * 72 + kj * 16 + l16] = f2bf(pv);
            }
        }
        __asm__ volatile("s_waitcnt lgkmcnt(0)" ::: "memory");

        bf16x8 ap0 = *reinterpret_cast<bf16x8*>(&Ps[(qs0 + l16) * 72 + quad * 8]);
        bf16x8 ap1 = *reinterpret_cast<bf16x8*>(&Ps[(qs0 + l16) * 72 + 32 + quad * 8]);
        lacc = __builtin_amdgcn_mfma_f32_16x16x32_bf16(ap0, ones, lacc, 0, 0, 0);
        lacc = __builtin_amdgcn_mfma_f32_16x16x32_bf16(ap1, ones, lacc, 0, 0, 0);
        #pragma unroll
        for (int cs = 0; cs < 4; ++cs) {
            bf16x8 bv0 = *reinterpret_cast<bf16x8*>(&Vs[(cs * 16 + l16) * 72 + quad * 8]);
            bf16x8 bv1 = *reinterpret_cast<bf16x8*>(&Vs[(cs * 16 + l16) * 72 + 32 + quad * 8]);
            oacc[cs] = __builtin_amdgcn_mfma_f32_16x16x32_bf16(ap0, bv0, oacc[cs], 0, 0, 0);
            oacc[cs] = __builtin_amdgcn_mfma_f32_16x16x32_bf16(ap1, bv1, oacc[cs], 0, 0, 0);
        }
    }

    float* Og = Oattn + ((size_t)b * N_ + q0) * 64;
    #pragma unroll
    for (int j = 0; j < 4; ++j) {
        int row = qs0 + quad * 4 + j;
        #pragma unroll
        for (int cs = 0; cs < 4; ++cs)
            unsafeAtomicAdd(&Og[row * 64 + cs * 16 + l16], oacc[cs][j]);
    }
    if (l16 == 0) {
        #pragma unroll
        for (int j = 0; j < 4; ++j)
            unsafeAtomicAdd(&lsum[b * N_ + q0 + qs0 + quad * 4 + j], lacc[j]);
    }
}

// ---------------------------------------------------------------- kernel 3
// MFMA epilogue: out[64,p] = Wo[64,64] @ t[64,p] + bo,
// t = Oattn*(gate/l) + x. Oattn is position-major = B-frag layout for free.
__global__ __launch_bounds__(256) void epi_kernel(
    const float* __restrict__ Oattn, const float* __restrict__ lsum,
    const float* __restrict__ x, const float* __restrict__ gate,
    const unsigned short* __restrict__ Wb, const float* __restrict__ bo,
    float* __restrict__ out)
{
    __shared__ float xs[64 * 68];   // [p][c] fp32, stride 68 (16B-aligned rows)
    __shared__ float os[64 * 68];   // out repack [o][p]

    int tid = threadIdx.x;
    int b  = blockIdx.x >> 6;
    int p0 = (blockIdx.x & 63) << 6;
    const float* xb = x + (size_t)b * (C_ * N_) + p0;

    for (int i = 0; i < 16; ++i) {
        int l = tid + i * 256;
        int c = l >> 6, p = l & 63;
        xs[p * 68 + c] = xb[(size_t)c * N_ + p];
    }
    __syncthreads();

    int lane = tid & 63;
    int wv   = __builtin_amdgcn_readfirstlane(tid >> 6);
    int quad = lane >> 4, l16 = lane & 15;
    int prow = wv * 16 + l16;
    int pos  = p0 + prow;

    float gi = gate[b * N_ + pos] / lsum[b * N_ + pos];
    const float* Og = Oattn + ((size_t)b * N_ + pos) * 64;

    // B-frags: t[p][c] bf16
    bf16x8 bt0, bt1;
    {
        float4 o0 = *reinterpret_cast<const float4*>(&Og[quad * 8]);
        float4 o1 = *reinterpret_cast<const float4*>(&Og[quad * 8 + 4]);
        float4 xa = *reinterpret_cast<float4*>(&xs[prow * 68 + quad * 8]);
        float4 xc = *reinterpret_cast<float4*>(&xs[prow * 68 + quad * 8 + 4]);
        bt0[0] = f2bf(fmaf(o0.x, gi, xa.x)); bt0[1] = f2bf(fmaf(o0.y, gi, xa.y));
        bt0[2] = f2bf(fmaf(o0.z, gi, xa.z)); bt0[3] = f2bf(fmaf(o0.w, gi, xa.w));
        bt0[4] = f2bf(fmaf(o1.x, gi, xc.x)); bt0[5] = f2bf(fmaf(o1.y, gi, xc.y));
        bt0[6] = f2bf(fmaf(o1.z, gi, xc.z)); bt0[7] = f2bf(fmaf(o1.w, gi, xc.w));
        float4 o2 = *reinterpret_cast<const float4*>(&Og[32 + quad * 8]);
        float4 o3 = *reinterpret_cast<const float4*>(&Og[32 + quad * 8 + 4]);
        float4 xe = *reinterpret_cast<float4*>(&xs[prow * 68 + 32 + quad * 8]);
        float4 xg = *reinterpret_cast<float4*>(&xs[prow * 68 + 32 + quad * 8 + 4]);
        bt1[0] = f2bf(fmaf(o2.x, gi, xe.x)); bt1[1] = f2bf(fmaf(o2.y, gi, xe.y));
        bt1[2] = f2bf(fmaf(o2.z, gi, xe.z)); bt1[3] = f2bf(fmaf(o2.w, gi, xe.w));
        bt1[4] = f2bf(fmaf(o3.x, gi, xg.x)); bt1[5] = f2bf(fmaf(o3.y, gi, xg.y));
        bt1[6] = f2bf(fmaf(o3.z, gi, xg.z)); bt1[7] = f2bf(fmaf(o3.w, gi, xg.w));
    }

    const unsigned short* Wob = Wb + 12288;   // Wo rows
    #pragma unroll
    for (int ot = 0; ot < 4; ++ot) {
        bf16x8 a0 = *reinterpret_cast<const bf16x8*>(&Wob[(ot * 16 + l16) * 64 + quad * 8]);
        bf16x8 a1 = *reinterpret_cast<const bf16x8*>(&Wob[(ot * 16 + l16) * 64 + 32 + quad * 8]);
        f32x4 c4 = (f32x4){0.f, 0.f, 0.f, 0.f};
        c4 = __builtin_amdgcn_mfma_f32_16x16x32_bf16(a0, bt0, c4, 0, 0, 0);
        c4 = __builtin_amdgcn_mfma_f32_16x16x32_bf16(a1, bt1, c4, 0, 0, 0);
        float4 bias = *reinterpret_cast<const float4*>(&bo[ot * 16 + quad * 4]);
        c4[0] += bias.x; c4[1] += bias.y; c4[2] += bias.z; c4[3] += bias.w;
        #pragma unroll
        for (int j = 0; j < 4; ++j)
            os[(ot * 16 + quad * 4 + j) * 68 + prow] = c4[j];
    }
    __syncthreads();

    // coalesced store: rows = out channel, 256B contiguous per row
    int row = tid >> 2;
    int pb  = (tid & 3) << 4;
    float* ob = out + ((size_t)b * 64 + row) * N_ + p0 + pb;
    #pragma unroll
    for (int k = 0; k < 4; ++k)
        *reinterpret_cast<float4*>(ob + k * 4) =
            *reinterpret_cast<float4*>(&os[row * 68 + pb + k * 4]);
}

// ---------------------------------------------------------------- launch
extern "C" void kernel_launch(void* const* d_in, const int* in_sizes, int n_in,
                              void* d_out, int out_size, void* d_ws, size_t ws_size,
                              hipStream_t stream)
{
    const float* x   = (const float*)d_in[0];
    const float* fp  = (const float*)d_in[1];
    const float* Wq  = (const float*)d_in[2];
    const float* bq  = (const float*)d_in[3];
    const float* Wk  = (const float*)d_in[4];
    const float* bk  = (const float*)d_in[5];
    const float* Wv  = (const float*)d_in[6];
    const float* bv  = (const float*)d_in[7];
    const float* Wo  = (const float*)d_in[8];
    const float* bo  = (const float*)d_in[9];
    const float* Wfp = (const float*)d_in[10];
    const float* bfp = (const float*)d_in[11];
    float* out = (float*)d_out;

    char* ws = (char*)d_ws;
    float* fp_proj = (float*)(ws);                                   // 1 KB
    float* gate    = (float*)(ws + 1024);                            // 64 KB
    unsigned short* Qb = (unsigned short*)(ws + 66560);              // 2 MB
    unsigned short* Kb = (unsigned short*)(ws + 66560 + 2097152);    // 2 MB
    unsigned short* Vb = (unsigned short*)(ws + 66560 + 2 * 2097152);// 2 MB
    float* Oattn = (float*)(ws + 66560 + 3 * 2097152);               // 4 MB
    float* lsum  = (float*)(ws + 66560 + 3 * 2097152 + 4194304);     // 64 KB
    unsigned short* Wb = (unsigned short*)(ws + 66560 + 3 * 2097152 + 4194304 + 65536); // 32 KB
    float* bs = (float*)(ws + 66560 + 3 * 2097152 + 4194304 + 65536 + 32768);          // 768 B

    hipMemsetAsync(Oattn, 0, 4194304 + 65536, stream);   // O + l accumulators

    hipLaunchKernelGGL(prep_kernel, dim3(65), dim3(256), 0, stream,
                       fp, Wfp, bfp, Wq, bq, Wk, bk, Wv, bv, Wo,
                       fp_proj, Wb, bs);
    hipLaunchKernelGGL(qkv_kernel, dim3(256), dim3(256), 0, stream,
                       x, Wb, bs, fp_proj, gate, Qb, Kb, Vb);
    hipLaunchKernelGGL(attn_kernel, dim3(1024), dim3(256), 0, stream,
                       Qb, Kb, Vb, Oattn, lsum);
    hipLaunchKernelGGL(epi_kernel, dim3(256), dim3(256), 0, stream,
                       Oattn, lsum, x, gate, Wb, bo, out);
}